// Round 19
// baseline (230.878 us; speedup 1.0000x reference)
//
#include <hip/hip_runtime.h>
#include <cmath>
#include <complex>
#include <algorithm>

#ifndef M_PI
#define M_PI 3.14159265358979323846
#endif

typedef _Float16 f16x8 __attribute__((ext_vector_type(8)));
typedef _Float16 f16x4 __attribute__((ext_vector_type(4)));
typedef float f32x4 __attribute__((ext_vector_type(4)));

// ---------------- coefficient structs (passed by value as kernel args) ---------
struct FiltArg {
  double b0[3], b1[3], b2[3], a1[3], a2[3];
  double zi0[3], zi1[3];
};
struct CorArg { double CA[16 * 6]; };  // CA[i][j] = output at step i from unit state e_j
struct EigArg {
  double Pm[36], Pinv[36];   // eigenbasis of the single-step state matrix A
  double czi[6];             // Pinv · (zi vector)
  double lam_re[3], lam_im[3];   // λ_s = p_s^16  (chunk = 16 steps)
  double lami_re[3], lami_im[3]; // λ_s^{-1}
};
struct FirArg { float h[526]; };  // 25 leading zeros + 501-tap kaiser-sinc, *UP

// ---------------- host-side filter design (exact replica of reference) --------
static void design_sos(FiltArg& sa) {
  const int order = 6;
  const double wn = 0.5 / 50.0;
  const double fs = 2.0;
  double warped = 2.0 * fs * std::tan(M_PI * wn / fs);
  std::complex<double> p[6];
  for (int i = 0; i < order; i++) {
    int m = -order + 1 + 2 * i;                      // -5,-3,-1,1,3,5
    p[i] = -std::exp(std::complex<double>(0.0, M_PI * m / (2.0 * order)));
  }
  std::complex<double> prod1(1, 0);
  for (int i = 0; i < 6; i++) prod1 *= -p[i];
  double k = (1.0 / prod1).real();
  for (int i = 0; i < 6; i++) p[i] = warped / p[i];
  const double fs2 = 2.0 * fs;
  std::complex<double> num(1, 0), den(1, 0);
  for (int i = 0; i < 6; i++) { num *= fs2; den *= (fs2 - p[i]); }
  k *= (num / den).real();
  for (int i = 0; i < 6; i++) p[i] = (fs2 + p[i]) / (fs2 - p[i]);
  std::complex<double> pp[3]; int n = 0;
  for (int i = 0; i < 6; i++) if (p[i].imag() > 0) pp[n++] = p[i];
  std::stable_sort(pp, pp + 3,
    [](const std::complex<double>& A, const std::complex<double>& B) {
      return std::fabs(std::abs(A) - 1.0) > std::fabs(std::abs(B) - 1.0);
    });
  double sos[3][6];
  for (int s = 0; s < 3; s++) {
    double g = (s == 0) ? k : 1.0;
    sos[s][0] = g; sos[s][1] = -2.0 * g; sos[s][2] = g;
    sos[s][3] = 1.0; sos[s][4] = -2.0 * pp[s].real(); sos[s][5] = std::norm(pp[s]);
  }
  double scale = 1.0;
  for (int s = 0; s < 3; s++) {
    double b0 = sos[s][0], b1 = sos[s][1], b2 = sos[s][2];
    double a1 = sos[s][4], a2 = sos[s][5];
    double det = 1.0 + a1 + a2;                      // det of [[1+a1,-1],[a2,1]]
    double r0 = b1 - a1 * b0, r1 = b2 - a2 * b0;
    double z0 = (r0 + r1) / det;
    double z1 = ((1.0 + a1) * r1 - a2 * r0) / det;
    sa.b0[s] = b0; sa.b1[s] = b1; sa.b2[s] = b2; sa.a1[s] = a1; sa.a2[s] = a2;
    sa.zi0[s] = scale * z0; sa.zi1[s] = scale * z1;
    scale *= (b0 + b1 + b2) / (1.0 + a1 + a2);
  }
}

static double host_step(const FiltArg& c, double z[6], double v) {
  for (int s = 0; s < 3; s++) {
    double y = c.b0[s] * v + z[2 * s];
    z[2 * s]     = c.b1[s] * v - c.a1[s] * y + z[2 * s + 1];
    z[2 * s + 1] = c.b2[s] * v - c.a2[s] * y;
    v = y;
  }
  return v;
}

static void build_filt(FiltArg& c, CorArg& co) {
  design_sos(c);
  for (int j = 0; j < 6; j++) {
    double z[6] = {0, 0, 0, 0, 0, 0};
    z[j] = 1.0;
    for (int i = 0; i < 16; i++) co.CA[i * 6 + j] = host_step(c, z, 0.0);
  }
}

static void build_eig(const FiltArg& c, EigArg& e) {
  double Pr[36];
  for (int s = 0; s < 3; s++) {
    double a1 = c.a1[s], a2 = c.a2[s];
    std::complex<double> disc = std::sqrt(std::complex<double>(a1 * a1 - 4.0 * a2, 0.0));
    std::complex<double> p = (-a1 + disc) / 2.0;
    if (p.imag() < 0) p = std::conj(p);
    std::complex<double> v[6] = {0, 0, 0, 0, 0, 0};
    v[2 * s] = 1.0;
    v[2 * s + 1] = a1 + p;
    std::complex<double> y = 1.0;
    for (int j = s + 1; j < 3; j++) {
      double b0j = c.b0[j], b1j = c.b1[j], b2j = c.b2[j];
      double a1j = c.a1[j], a2j = c.a2[j];
      std::complex<double> det = p * p + a1j * p + a2j;
      std::complex<double> r0 = (b1j - a1j * b0j) * y;
      std::complex<double> r1 = (b2j - a2j * b0j) * y;
      std::complex<double> z0 = (p * r0 + r1) / det;
      std::complex<double> z1 = ((p + a1j) * r1 - a2j * r0) / det;
      v[2 * j] = z0; v[2 * j + 1] = z1;
      y = b0j * y + z0;
    }
    for (int i = 0; i < 6; i++) {
      Pr[i * 6 + 2 * s]     = v[i].real();
      Pr[i * 6 + 2 * s + 1] = v[i].imag();
    }
    std::complex<double> lam = std::pow(p, 16);
    e.lam_re[s] = lam.real(); e.lam_im[s] = lam.imag();
    std::complex<double> li = 1.0 / lam;
    e.lami_re[s] = li.real(); e.lami_im[s] = li.imag();
  }
  for (int i = 0; i < 36; i++) e.Pm[i] = Pr[i];
  double M[6][12];
  for (int i = 0; i < 6; i++)
    for (int j = 0; j < 6; j++) { M[i][j] = Pr[i * 6 + j]; M[i][6 + j] = (i == j) ? 1.0 : 0.0; }
  for (int col = 0; col < 6; col++) {
    int piv = col;
    for (int i = col + 1; i < 6; i++)
      if (std::fabs(M[i][col]) > std::fabs(M[piv][col])) piv = i;
    if (piv != col) for (int j = 0; j < 12; j++) std::swap(M[col][j], M[piv][j]);
    double d = M[col][col];
    for (int j = 0; j < 12; j++) M[col][j] /= d;
    for (int i = 0; i < 6; i++) if (i != col) {
      double f = M[i][col];
      for (int j = 0; j < 12; j++) M[i][j] -= f * M[col][j];
    }
  }
  for (int i = 0; i < 6; i++)
    for (int j = 0; j < 6; j++) e.Pinv[i * 6 + j] = M[i][6 + j];
  double zv[6];
  for (int s = 0; s < 3; s++) { zv[2 * s] = c.zi0[s]; zv[2 * s + 1] = c.zi1[s]; }
  for (int i = 0; i < 6; i++) {
    double sum = 0.0;
    for (int j = 0; j < 6; j++) sum += e.Pinv[i * 6 + j] * zv[j];
    e.czi[i] = sum;
  }
}

static double bessel_i0(double x) {
  double s = 1.0, t = 1.0;
  for (int k = 1; k < 64; k++) {
    double u = x / (2.0 * k);
    t *= u * u; s += t;
    if (t < 1e-18 * s) break;
  }
  return s;
}

static void design_fir(FirArg& fa) {
  double h[501];
  const double fc = 1.0 / 25.0;
  double denom = bessel_i0(5.0);
  double sum = 0.0;
  for (int nn = 0; nn < 501; nn++) {
    double m = nn - 250.0;
    double xx = fc * m;
    double snc = (nn == 250) ? 1.0 : std::sin(M_PI * xx) / (M_PI * xx);
    double r = (2.0 * nn) / 500.0 - 1.0;
    double w = bessel_i0(5.0 * std::sqrt(std::max(0.0, 1.0 - r * r))) / denom;
    h[nn] = fc * snc * w; sum += h[nn];
  }
  for (int nn = 0; nn < 25; nn++) fa.h[nn] = 0.0f;          // n_pre_pad = 25
  for (int nn = 0; nn < 501; nn++) fa.h[25 + nn] = (float)(h[nn] / sum * 16.0);
}

// ---------------- device helpers ----------------
__device__ inline double waveReduceSum(double v) {
  #pragma unroll
  for (int off = 32; off > 0; off >>= 1) v += __shfl_down(v, off, 64);
  return v;
}

__device__ inline void cpow_int(double br, double bi, int n, double& rr_, double& ri_) {
  double rr = 1.0, ri = 0.0;
  while (n) {
    if (n & 1) { double t = rr * br - ri * bi; ri = rr * bi + ri * br; rr = t; }
    double t2 = br * br - bi * bi; bi = 2.0 * br * bi; br = t2;
    n >>= 1;
  }
  rr_ = rr; ri_ = ri;
}

// ---------------- kernel 1: chansel + demean, PE table, out-zero (merged) -----
__global__ __launch_bounds__(256) void k_chansel_pe(const float* __restrict__ x,
                                                    float* __restrict__ xs,
                                                    float* __restrict__ pe,
                                                    float* __restrict__ out) {
  int gid = blockIdx.x;
  if (gid < 500) {
    int idx = gid * 256 + threadIdx.x;
    int b = idx / 2000, t = idx % 2000;
    const int ch[10] = {126, 125, 48, 112, 67, 93, 10, 61, 39, 108};
    const float* xb = x + (size_t)b * 128 * 2000;
    float v[10]; float s = 0.f;
    #pragma unroll
    for (int c = 0; c < 10; c++) { v[c] = xb[ch[c] * 2000 + t]; s += v[c]; }
    s *= 0.1f;
    #pragma unroll
    for (int c = 0; c < 10; c++) xs[((size_t)b * 10 + c) * 2000 + t] = v[c] - s;
  } else {
    int i = (gid - 500) * 256 + threadIdx.x;    // [0, 20480)
    int t = i >> 4, d = i & 15, j = d >> 1;
    double div = exp(-((double)(2 * j)) * 0.5756462732485114); // ln(10000)/16
    double a = (double)t * div;
    pe[i] = (float)((d & 1) ? cos(a) : sin(a));
    if (gid == 579 && threadIdx.x < 64) out[threadIdx.x] = 0.f;
  }
}

// ---------------- kernel 2: filtfilt, 128 chunks x 16 steps, eigen prefix -----
#define XR(t) xr[(t) + ((t) >> 5)]
#define YF(t) yf[(t) + ((t) >> 5)]
__global__ __launch_bounds__(128) void k_filtfilt(float* __restrict__ xs,
                                                  FiltArg c, CorArg co, EigArg eg) {
  __shared__ float xr[2112];      // extended input seq (padded)
  __shared__ double yf[2112];     // corrected forward output (padded)
  __shared__ double wsum[3][2];   // wave0 inclusive totals per section
  int r = blockIdx.x;
  int gk = threadIdx.x;           // global chunk id 0..127
  int lane = gk & 63;
  int wv = gk >> 6;
  float* x = xs + (size_t)r * 2000;

  float x0f = x[0], xlf = x[1999];
  for (int t = gk; t < 2048; t += 128) {
    float v;
    if (t < 21)        v = 2.f * x0f - x[21 - t];
    else if (t < 2021) v = x[t - 21];
    else if (t < 2042) v = 2.f * xlf - x[4019 - t];
    else               v = 0.f;
    XR(t) = v;
  }
  __syncthreads();

  double b0[3], b1[3], b2[3], a1[3], a2[3];
  #pragma unroll
  for (int s = 0; s < 3; s++) {
    b0[s] = c.b0[s]; b1[s] = c.b1[s]; b2[s] = c.b2[s];
    a1[s] = c.a1[s]; a2[s] = c.a2[s];
  }
  auto step = [&](double* z, double v) -> double {
    #pragma unroll
    for (int s = 0; s < 3; s++) {
      double y = b0[s] * v + z[2 * s];
      z[2 * s]     = b1[s] * v - a1[s] * y + z[2 * s + 1];
      z[2 * s + 1] = b2[s] * v - a2[s] * y;
      v = y;
    }
    return v;
  };

  auto eigscan = [&](double seed, const double* F, double* zst) {
    double G[6];
    #pragma unroll
    for (int i = 0; i < 6; i++) {
      double s = 0.0;
      #pragma unroll
      for (int j = 0; j < 6; j++) s += eg.Pinv[i * 6 + j] * F[j];
      G[i] = s;
    }
    double tre[3], tim[3], sre[3], sim[3];
    #pragma unroll
    for (int s3 = 0; s3 < 3; s3++) {
      double gre = G[2 * s3], gim = -G[2 * s3 + 1];
      double mre, mim;                                  // λ^{-gk}
      cpow_int(eg.lami_re[s3], eg.lami_im[s3], gk, mre, mim);
      tre[s3] = mre * gre - mim * gim;
      tim[s3] = mre * gim + mim * gre;
      double pr = tre[s3], pi = tim[s3];
      #pragma unroll
      for (int off = 1; off < 64; off <<= 1) {
        double ore = __shfl_up(pr, off, 64);
        double oim = __shfl_up(pi, off, 64);
        pr += (lane >= off) ? ore : 0.0;
        pi += (lane >= off) ? oim : 0.0;
      }
      sre[s3] = pr; sim[s3] = pi;
      if (wv == 0 && lane == 63) { wsum[s3][0] = pr; wsum[s3][1] = pi; }
    }
    __syncthreads();
    double coord[6];
    #pragma unroll
    for (int s3 = 0; s3 < 3; s3++) {
      double inc_re = sre[s3] + (wv ? wsum[s3][0] : 0.0);
      double inc_im = sim[s3] + (wv ? wsum[s3][1] : 0.0);
      double Sre = inc_re - tre[s3], Sim = inc_im - tim[s3];
      double c0re = seed * eg.czi[2 * s3];
      double c0im = -seed * eg.czi[2 * s3 + 1];
      double lkre, lkim;
      cpow_int(eg.lam_re[s3], eg.lam_im[s3], gk, lkre, lkim);
      double lm1re = lkre * eg.lami_re[s3] - lkim * eg.lami_im[s3];
      double lm1im = lkre * eg.lami_im[s3] + lkim * eg.lami_re[s3];
      if (gk == 0) { lm1re = 0.0; lm1im = 0.0; }
      double cre = lkre * c0re - lkim * c0im + lm1re * Sre - lm1im * Sim;
      double cim = lkre * c0im + lkim * c0re + lm1re * Sim + lm1im * Sre;
      coord[2 * s3] = cre;
      coord[2 * s3 + 1] = -cim;
    }
    #pragma unroll
    for (int i = 0; i < 6; i++) {
      double s = 0.0;
      #pragma unroll
      for (int j = 0; j < 6; j++) s += eg.Pm[i * 6 + j] * coord[j];
      zst[i] = s;
    }
  };

  int t0 = gk * 16;
  double z[6], yreg[16], zst[6];

  #pragma unroll
  for (int i = 0; i < 6; i++) z[i] = 0.0;
  for (int i = 0; i < 16; i++) yreg[i] = step(z, (double)XR(t0 + i));
  eigscan((double)XR(0), z, zst);
  for (int i = 0; i < 16; i++) {
    double corr = 0.0;
    #pragma unroll
    for (int j = 0; j < 6; j++) corr += co.CA[i * 6 + j] * zst[j];
    YF(t0 + i) = yreg[i] + corr;
  }
  __syncthreads();

  auto rin = [&](int j) -> double { return (j <= 2041) ? YF(2041 - j) : 0.0; };
  double seedB = YF(2041);
  #pragma unroll
  for (int i = 0; i < 6; i++) z[i] = 0.0;
  for (int i = 0; i < 16; i++) yreg[i] = step(z, rin(t0 + i));
  eigscan(seedB, z, zst);
  for (int i = 0; i < 16; i++) {
    int j = t0 + i;
    if (j >= 21 && j <= 2020) {
      double corr = 0.0;
      #pragma unroll
      for (int jj = 0; jj < 6; jj++) corr += co.CA[i * 6 + jj] * zst[jj];
      x[2020 - j] = (float)(yreg[i] + corr);   // reversed + trimmed
    }
  }
}

// ---------------- kernel 3: polyphase resample + tanh + per-row normalize ----
__global__ __launch_bounds__(256) void k_resample_norm(const float* __restrict__ xf,
                                                       float* __restrict__ xn,
                                                       FirArg fa) {
  __shared__ float xl[2000];
  __shared__ float hl[526];
  int r = blockIdx.x;                         // 640 rows
  const float* x = xf + (size_t)r * 2000;
  for (int i = threadIdx.x; i < 2000; i += 256) xl[i] = x[i];
  for (int i = threadIdx.x; i < 526; i += 256) hl[i] = fa.h[i];
  __syncthreads();
  float vals[5];
  #pragma unroll
  for (int kk = 0; kk < 5; kk++) {
    int o = threadIdx.x + kk * 256;           // 1280 outputs per row
    int P = 25 * (o + 11);
    int phase = P & 15;
    float acc = 0.f;
    for (int m = phase; m <= 525; m += 16) {
      int idx = (P - m) >> 4;
      if (idx >= 0 && idx < 2000) acc += hl[m] * xl[idx];
    }
    vals[kk] = tanhf(acc);
  }
  double s = 0.0, ss = 0.0;
  #pragma unroll
  for (int kk = 0; kk < 5; kk++) {
    s += (double)vals[kk]; ss += (double)vals[kk] * (double)vals[kk];
  }
  s = waveReduceSum(s); ss = waveReduceSum(ss);
  __shared__ double red[8];
  int wid = threadIdx.x >> 6, lane = threadIdx.x & 63;
  if (lane == 0) { red[wid] = s; red[4 + wid] = ss; }
  __syncthreads();
  double S = red[0] + red[1] + red[2] + red[3];
  double SS = red[4] + red[5] + red[6] + red[7];
  double mean = S / 1280.0;
  double var = (SS - 1280.0 * mean * mean) / 1279.0;
  double sd = fmax(sqrt(fmax(var, 0.0)), 1e-6);
  float fmean = (float)mean, finv = (float)(1.0 / sd);
  #pragma unroll
  for (int kk = 0; kk < 5; kk++)
    xn[(size_t)r * 1280 + threadIdx.x + kk * 256] = (vals[kk] - fmean) * finv;
}

// ---------------- kernel 4: conv1d + relu + LN + PE + QKV (K,V emitted f16) ---
__global__ __launch_bounds__(256) void k_conv_ln_pe_qkv(const float* __restrict__ xn,
    const float* __restrict__ cw, const float* __restrict__ cb,
    const float* __restrict__ g0, const float* __restrict__ bt0,
    const float* __restrict__ wqkv, const float* __restrict__ bqkv,
    const float* __restrict__ pe,
    float* __restrict__ x0, float* __restrict__ Q,
    _Float16* __restrict__ Kp, _Float16* __restrict__ Vt_g) {
  __shared__ float w[480], bias[16], gg[16], gb[16];
  __shared__ float wq[768], bq[48];
  for (int i = threadIdx.x; i < 480; i += 256) w[i] = cw[i];
  for (int i = threadIdx.x; i < 768; i += 256) wq[i] = wqkv[i];
  if (threadIdx.x < 16) {
    bias[threadIdx.x] = cb[threadIdx.x];
    gg[threadIdx.x] = g0[threadIdx.x];
    gb[threadIdx.x] = bt0[threadIdx.x];
  }
  if (threadIdx.x < 48) bq[threadIdx.x] = bqkv[threadIdx.x];
  __syncthreads();
  int idx = blockIdx.x * 256 + threadIdx.x;
  int b = idx / 1280, t = idx % 1280;
  const float* xb = xn + (size_t)b * 10 * 1280;
  float in[10][3];
  #pragma unroll
  for (int i = 0; i < 10; i++)
    #pragma unroll
    for (int k = 0; k < 3; k++) {
      int tt = t - 1 + k;
      in[i][k] = (tt >= 0 && tt < 1280) ? xb[i * 1280 + tt] : 0.f;
    }
  float o[16];
  #pragma unroll
  for (int oc = 0; oc < 16; oc++) {
    float a = bias[oc];
    #pragma unroll
    for (int i = 0; i < 10; i++)
      #pragma unroll
      for (int k = 0; k < 3; k++) a += in[i][k] * w[oc * 30 + i * 3 + k];
    o[oc] = fmaxf(a, 0.f);
  }
  float mu = 0.f;
  #pragma unroll
  for (int d = 0; d < 16; d++) mu += o[d];
  mu *= (1.f / 16.f);
  float var = 0.f;
  #pragma unroll
  for (int d = 0; d < 16; d++) { float dd = o[d] - mu; var += dd * dd; }
  var *= (1.f / 16.f);
  float inv = 1.f / sqrtf(var + 1e-5f);
  float xv[16];
  float* outp = x0 + (size_t)idx * 16;
  const float* pep = pe + t * 16;
  #pragma unroll
  for (int d = 0; d < 16; d++) {
    xv[d] = (o[d] - mu) * inv * gg[d] + gb[d] + pep[d];
    outp[d] = xv[d];
  }
  float* qp = Q + (size_t)idx * 16;
  #pragma unroll
  for (int j = 0; j < 16; j++) {
    float a = bq[j];
    #pragma unroll
    for (int d = 0; d < 16; d++) a += xv[d] * wq[j * 16 + d];
    qp[j] = a;
  }
  {
    _Float16* kp = Kp + (size_t)idx * 32;
    #pragma unroll
    for (int j = 0; j < 16; j++) {
      float a = bq[16 + j];
      #pragma unroll
      for (int d = 0; d < 16; d++) a += xv[d] * wq[(16 + j) * 16 + d];
      kp[j] = (_Float16)a;
    }
    f16x8 zz;
    #pragma unroll
    for (int j = 0; j < 8; j++) zz[j] = (_Float16)0.f;
    *(f16x8*)&kp[16] = zz;
    *(f16x8*)&kp[24] = zz;
  }
  {
    _Float16* vt = Vt_g + (size_t)b * 16 * 1280 + t;
    #pragma unroll
    for (int j = 0; j < 16; j++) {
      float a = bq[32 + j];
      #pragma unroll
      for (int d = 0; d < 16; d++) a += xv[d] * wq[(32 + j) * 16 + d];
      vt[j * 1280] = (_Float16)a;
    }
  }
}

// ---------------- kernel 5: MFMA attention + combine + pool (fused) -----------
#define ATT_SHIFT 12.0f
__global__ __launch_bounds__(256) void k_attn_combine(const float* __restrict__ Q,
    const _Float16* __restrict__ Kp, const _Float16* __restrict__ Vt_g,
    const float* __restrict__ x0,
    const float* __restrict__ wo, const float* __restrict__ bo,
    const float* __restrict__ w1, const float* __restrict__ b1,
    const float* __restrict__ w2, const float* __restrict__ b2,
    const float* __restrict__ g1, const float* __restrict__ bb1,
    const float* __restrict__ g2, const float* __restrict__ bb2,
    const float* __restrict__ wfc, const float* __restrict__ bfc,
    float* __restrict__ out) {
  __shared__ __align__(16) _Float16 Ks2[64 * 32];    // [key][d0..31]
  __shared__ __align__(16) _Float16 Vt[16 * 72];     // [d][key]
  __shared__ __align__(16) _Float16 Pld[4][16 * 40]; // per-wave [qrow][key32]
  __shared__ float Aly[64][17];                      // attn out rows (padded)
  __shared__ float swo[256], sw1[512], sw2[512];
  __shared__ float sbo[16], sb1[32], sb2[16], sg1[16], sbb1[16], sg2[16], sbb2[16];
  __shared__ float swf[16];
  int tid = threadIdx.x;
  int b  = blockIdx.x / 20;
  int rg = blockIdx.x % 20;
  int wv = tid >> 6;
  int lane = tid & 63;
  int col = lane & 15;
  int quad = lane >> 4;
  size_t base = (size_t)b * 1280;
  int row0 = rg * 64 + wv * 16;

  // stage combine weights (overlaps first tile staging)
  swo[tid] = wo[tid];
  for (int i = tid; i < 512; i += 256) { sw1[i] = w1[i]; sw2[i] = w2[i]; }
  if (tid < 16) {
    sbo[tid] = bo[tid]; sb2[tid] = b2[tid];
    sg1[tid] = g1[tid]; sbb1[tid] = bb1[tid];
    sg2[tid] = g2[tid]; sbb2[tid] = bb2[tid];
    swf[tid] = wfc[tid];
  }
  if (tid < 32) sb1[tid] = b1[tid];

  f16x8 qf;
  #pragma unroll
  for (int j = 0; j < 8; j++) qf[j] = (_Float16)0.f;
  if (quad < 2) {
    const float* qp = Q + (base + row0 + col) * 16 + quad * 8;
    #pragma unroll
    for (int j = 0; j < 8; j++) qf[j] = (_Float16)(0.25f * qp[j]);
  }
  f32x4 oacc = {0.f, 0.f, 0.f, 0.f};
  float lacc = 0.f;

  const _Float16* vt_b = Vt_g + (size_t)b * 16 * 1280;

  for (int s = 0; s < 20; s++) {
    __syncthreads();
    *(f16x8*)&Ks2[tid * 8] =
        *(const f16x8*)(Kp + (base + s * 64) * 32 + tid * 8);
    if (tid < 128) {
      int d = tid >> 3, qc = tid & 7;
      *(f16x8*)&Vt[d * 72 + qc * 8] =
          *(const f16x8*)(vt_b + d * 1280 + s * 64 + qc * 8);
    }
    __syncthreads();
    #pragma unroll
    for (int c = 0; c < 2; c++) {
      #pragma unroll
      for (int t = 0; t < 2; t++) {
        int keyoff = c * 32 + t * 16;
        f16x8 af = *(f16x8*)&Ks2[(keyoff + col) * 32 + quad * 8];
        f32x4 sf = {0.f, 0.f, 0.f, 0.f};
        sf = __builtin_amdgcn_mfma_f32_16x16x32_f16(af, qf, sf, 0, 0, 0);
        f16x4 ph;
        float psum = 0.f;
        #pragma unroll
        for (int r = 0; r < 4; r++) {
          float p = __expf(sf[r] - ATT_SHIFT);
          psum += p;
          ph[r] = (_Float16)p;
        }
        lacc += psum;
        *(f16x4*)&Pld[wv][col * 40 + t * 16 + quad * 4] = ph;
      }
      __syncthreads();
      f16x8 pf = *(f16x8*)&Pld[wv][col * 40 + quad * 8];
      f16x8 vf = *(f16x8*)&Vt[col * 72 + c * 32 + quad * 8];
      oacc = __builtin_amdgcn_mfma_f32_16x16x32_f16(pf, vf, oacc, 0, 0, 0);
      __syncthreads();
    }
  }
  lacc += __shfl_xor(lacc, 16, 64);
  lacc += __shfl_xor(lacc, 32, 64);
  #pragma unroll
  for (int r = 0; r < 4; r++) {
    float lr = __shfl(lacc, quad * 4 + r, 64);
    Aly[wv * 16 + quad * 4 + r][col] = oacc[r] / lr;
  }
  __syncthreads();

  // ---- epilogue: wave 0, one thread per row ----
  if (tid < 64) {
    int grow = rg * 64 + tid;                 // row within batch
    size_t goff = (base + grow) * 16;
    float a[16];
    #pragma unroll
    for (int d = 0; d < 16; d++) a[d] = Aly[tid][d];
    float h[16];
    const float* xr = x0 + goff;
    #pragma unroll
    for (int d = 0; d < 16; d++) {
      float o = sbo[d];
      #pragma unroll
      for (int e = 0; e < 16; e++) o += a[e] * swo[d * 16 + e];
      h[d] = xr[d] + o;
    }
    float mu = 0.f;
    #pragma unroll
    for (int d = 0; d < 16; d++) mu += h[d];
    mu *= (1.f / 16.f);
    float var = 0.f;
    #pragma unroll
    for (int d = 0; d < 16; d++) { float dd = h[d] - mu; var += dd * dd; }
    var *= (1.f / 16.f);
    float inv = 1.f / sqrtf(var + 1e-5f);
    float x1[16];
    #pragma unroll
    for (int d = 0; d < 16; d++) x1[d] = (h[d] - mu) * inv * sg1[d] + sbb1[d];
    float t1[32];
    #pragma unroll
    for (int j = 0; j < 32; j++) {
      float u = sb1[j];
      #pragma unroll
      for (int d = 0; d < 16; d++) u += x1[d] * sw1[j * 16 + d];
      t1[j] = fmaxf(u, 0.f);
    }
    float h2[16];
    #pragma unroll
    for (int d = 0; d < 16; d++) {
      float u = sb2[d];
      #pragma unroll
      for (int j = 0; j < 32; j++) u += t1[j] * sw2[d * 32 + j];
      h2[d] = x1[d] + u;
    }
    mu = 0.f;
    #pragma unroll
    for (int d = 0; d < 16; d++) mu += h2[d];
    mu *= (1.f / 16.f);
    var = 0.f;
    #pragma unroll
    for (int d = 0; d < 16; d++) { float dd = h2[d] - mu; var += dd * dd; }
    var *= (1.f / 16.f);
    inv = 1.f / sqrtf(var + 1e-5f);
    float pv = 0.f;
    #pragma unroll
    for (int d = 0; d < 16; d++)
      pv += ((h2[d] - mu) * inv * sg2[d] + sbb2[d]) * swf[d];
    double part = waveReduceSum((double)pv);
    if (tid == 0) {
      float add = (float)(part / 1280.0);
      if (blockIdx.x % 20 == 0) add += bfc[0];
      atomicAdd(&out[b], add);
    }
  }
}

// ---------------- launch ------------------------------------------------------
extern "C" void kernel_launch(void* const* d_in, const int* in_sizes, int n_in,
                              void* d_out, int out_size, void* d_ws, size_t ws_size,
                              hipStream_t stream) {
  const float* x    = (const float*)d_in[0];
  const float* cw   = (const float*)d_in[1];
  const float* cb   = (const float*)d_in[2];
  const float* g0   = (const float*)d_in[3];
  const float* bt0  = (const float*)d_in[4];
  const float* wqkv = (const float*)d_in[5];
  const float* bqkv = (const float*)d_in[6];
  const float* wo   = (const float*)d_in[7];
  const float* bo   = (const float*)d_in[8];
  const float* w1   = (const float*)d_in[9];
  const float* b1   = (const float*)d_in[10];
  const float* w2   = (const float*)d_in[11];
  const float* b2   = (const float*)d_in[12];
  const float* g1   = (const float*)d_in[13];
  const float* bb1  = (const float*)d_in[14];
  const float* g2   = (const float*)d_in[15];
  const float* bb2  = (const float*)d_in[16];
  const float* wfc  = (const float*)d_in[17];
  const float* bfc  = (const float*)d_in[18];
  float* out = (float*)d_out;

  float* ws = (float*)d_ws;
  float* xs = ws;                       // 640*2000 = 1,280,000 (filtered in-place)
  float* y1 = xs + 1280000;             // spacer (dead)
  float* xn = y1 + 1306880;             // 640*1280   =   819,200
  float* x0 = xn + 819200;              // 64*1280*16 = 1,310,720
  float* Q  = x0 + 1310720;
  _Float16* Kp   = (_Float16*)(Q + 1310720);      // 64*1280*32 f16 = 1,310,720 floats
  _Float16* Vt_g = (_Float16*)(Q + 2621440);      // 64*16*1280 f16 =   655,360 floats
  float* pe = Q + 2621440 + 655360;     // 1280*16 = 20,480  (total ~34 MB)

  FiltArg fc; CorArg co; EigArg eg; FirArg fa;
  build_filt(fc, co);
  build_eig(fc, eg);
  design_fir(fa);

  k_chansel_pe<<<580, 256, 0, stream>>>(x, xs, pe, out);
  k_filtfilt<<<640, 128, 0, stream>>>(xs, fc, co, eg);
  k_resample_norm<<<640, 256, 0, stream>>>(xs, xn, fa);
  k_conv_ln_pe_qkv<<<320, 256, 0, stream>>>(xn, cw, cb, g0, bt0, wqkv, bqkv,
                                            pe, x0, Q, Kp, Vt_g);
  k_attn_combine<<<1280, 256, 0, stream>>>(Q, Kp, Vt_g, x0, wo, bo, w1, b1,
                                           w2, b2, g1, bb1, g2, bb2, wfc, bfc,
                                           out);
}

// Round 20
// 229.652 us; speedup vs baseline: 1.0053x; 1.0053x over previous
//
#include <hip/hip_runtime.h>
#include <cmath>
#include <complex>
#include <algorithm>

#ifndef M_PI
#define M_PI 3.14159265358979323846
#endif

typedef _Float16 f16x8 __attribute__((ext_vector_type(8)));
typedef _Float16 f16x4 __attribute__((ext_vector_type(4)));
typedef float f32x4 __attribute__((ext_vector_type(4)));

// ---------------- coefficient structs (passed by value as kernel args) ---------
struct FiltArg {
  double b0[3], b1[3], b2[3], a1[3], a2[3];
  double zi0[3], zi1[3];
};
struct CorArg { double CA[16 * 6]; };  // CA[i][j] = output at step i from unit state e_j
struct EigArg {
  double Pm[36], Pinv[36];   // eigenbasis of the single-step state matrix A
  double czi[6];             // Pinv · (zi vector)
  double lam_re[3], lam_im[3];   // λ_s = p_s^16  (chunk = 16 steps)
  double lami_re[3], lami_im[3]; // λ_s^{-1}
};
struct FirArg { float h[526]; };  // 25 leading zeros + 501-tap kaiser-sinc, *UP

// ---------------- host-side filter design (exact replica of reference) --------
static void design_sos(FiltArg& sa) {
  const int order = 6;
  const double wn = 0.5 / 50.0;
  const double fs = 2.0;
  double warped = 2.0 * fs * std::tan(M_PI * wn / fs);
  std::complex<double> p[6];
  for (int i = 0; i < order; i++) {
    int m = -order + 1 + 2 * i;                      // -5,-3,-1,1,3,5
    p[i] = -std::exp(std::complex<double>(0.0, M_PI * m / (2.0 * order)));
  }
  std::complex<double> prod1(1, 0);
  for (int i = 0; i < 6; i++) prod1 *= -p[i];
  double k = (1.0 / prod1).real();
  for (int i = 0; i < 6; i++) p[i] = warped / p[i];
  const double fs2 = 2.0 * fs;
  std::complex<double> num(1, 0), den(1, 0);
  for (int i = 0; i < 6; i++) { num *= fs2; den *= (fs2 - p[i]); }
  k *= (num / den).real();
  for (int i = 0; i < 6; i++) p[i] = (fs2 + p[i]) / (fs2 - p[i]);
  std::complex<double> pp[3]; int n = 0;
  for (int i = 0; i < 6; i++) if (p[i].imag() > 0) pp[n++] = p[i];
  std::stable_sort(pp, pp + 3,
    [](const std::complex<double>& A, const std::complex<double>& B) {
      return std::fabs(std::abs(A) - 1.0) > std::fabs(std::abs(B) - 1.0);
    });
  double sos[3][6];
  for (int s = 0; s < 3; s++) {
    double g = (s == 0) ? k : 1.0;
    sos[s][0] = g; sos[s][1] = -2.0 * g; sos[s][2] = g;
    sos[s][3] = 1.0; sos[s][4] = -2.0 * pp[s].real(); sos[s][5] = std::norm(pp[s]);
  }
  double scale = 1.0;
  for (int s = 0; s < 3; s++) {
    double b0 = sos[s][0], b1 = sos[s][1], b2 = sos[s][2];
    double a1 = sos[s][4], a2 = sos[s][5];
    double det = 1.0 + a1 + a2;                      // det of [[1+a1,-1],[a2,1]]
    double r0 = b1 - a1 * b0, r1 = b2 - a2 * b0;
    double z0 = (r0 + r1) / det;
    double z1 = ((1.0 + a1) * r1 - a2 * r0) / det;
    sa.b0[s] = b0; sa.b1[s] = b1; sa.b2[s] = b2; sa.a1[s] = a1; sa.a2[s] = a2;
    sa.zi0[s] = scale * z0; sa.zi1[s] = scale * z1;
    scale *= (b0 + b1 + b2) / (1.0 + a1 + a2);
  }
}

static double host_step(const FiltArg& c, double z[6], double v) {
  for (int s = 0; s < 3; s++) {
    double y = c.b0[s] * v + z[2 * s];
    z[2 * s]     = c.b1[s] * v - c.a1[s] * y + z[2 * s + 1];
    z[2 * s + 1] = c.b2[s] * v - c.a2[s] * y;
    v = y;
  }
  return v;
}

static void build_filt(FiltArg& c, CorArg& co) {
  design_sos(c);
  for (int j = 0; j < 6; j++) {
    double z[6] = {0, 0, 0, 0, 0, 0};
    z[j] = 1.0;
    for (int i = 0; i < 16; i++) co.CA[i * 6 + j] = host_step(c, z, 0.0);
  }
}

static void build_eig(const FiltArg& c, EigArg& e) {
  double Pr[36];
  for (int s = 0; s < 3; s++) {
    double a1 = c.a1[s], a2 = c.a2[s];
    std::complex<double> disc = std::sqrt(std::complex<double>(a1 * a1 - 4.0 * a2, 0.0));
    std::complex<double> p = (-a1 + disc) / 2.0;
    if (p.imag() < 0) p = std::conj(p);
    std::complex<double> v[6] = {0, 0, 0, 0, 0, 0};
    v[2 * s] = 1.0;
    v[2 * s + 1] = a1 + p;
    std::complex<double> y = 1.0;
    for (int j = s + 1; j < 3; j++) {
      double b0j = c.b0[j], b1j = c.b1[j], b2j = c.b2[j];
      double a1j = c.a1[j], a2j = c.a2[j];
      std::complex<double> det = p * p + a1j * p + a2j;
      std::complex<double> r0 = (b1j - a1j * b0j) * y;
      std::complex<double> r1 = (b2j - a2j * b0j) * y;
      std::complex<double> z0 = (p * r0 + r1) / det;
      std::complex<double> z1 = ((p + a1j) * r1 - a2j * r0) / det;
      v[2 * j] = z0; v[2 * j + 1] = z1;
      y = b0j * y + z0;
    }
    for (int i = 0; i < 6; i++) {
      Pr[i * 6 + 2 * s]     = v[i].real();
      Pr[i * 6 + 2 * s + 1] = v[i].imag();
    }
    std::complex<double> lam = std::pow(p, 16);
    e.lam_re[s] = lam.real(); e.lam_im[s] = lam.imag();
    std::complex<double> li = 1.0 / lam;
    e.lami_re[s] = li.real(); e.lami_im[s] = li.imag();
  }
  for (int i = 0; i < 36; i++) e.Pm[i] = Pr[i];
  double M[6][12];
  for (int i = 0; i < 6; i++)
    for (int j = 0; j < 6; j++) { M[i][j] = Pr[i * 6 + j]; M[i][6 + j] = (i == j) ? 1.0 : 0.0; }
  for (int col = 0; col < 6; col++) {
    int piv = col;
    for (int i = col + 1; i < 6; i++)
      if (std::fabs(M[i][col]) > std::fabs(M[piv][col])) piv = i;
    if (piv != col) for (int j = 0; j < 12; j++) std::swap(M[col][j], M[piv][j]);
    double d = M[col][col];
    for (int j = 0; j < 12; j++) M[col][j] /= d;
    for (int i = 0; i < 6; i++) if (i != col) {
      double f = M[i][col];
      for (int j = 0; j < 12; j++) M[i][j] -= f * M[col][j];
    }
  }
  for (int i = 0; i < 6; i++)
    for (int j = 0; j < 6; j++) e.Pinv[i * 6 + j] = M[i][6 + j];
  double zv[6];
  for (int s = 0; s < 3; s++) { zv[2 * s] = c.zi0[s]; zv[2 * s + 1] = c.zi1[s]; }
  for (int i = 0; i < 6; i++) {
    double sum = 0.0;
    for (int j = 0; j < 6; j++) sum += e.Pinv[i * 6 + j] * zv[j];
    e.czi[i] = sum;
  }
}

static double bessel_i0(double x) {
  double s = 1.0, t = 1.0;
  for (int k = 1; k < 64; k++) {
    double u = x / (2.0 * k);
    t *= u * u; s += t;
    if (t < 1e-18 * s) break;
  }
  return s;
}

static void design_fir(FirArg& fa) {
  double h[501];
  const double fc = 1.0 / 25.0;
  double denom = bessel_i0(5.0);
  double sum = 0.0;
  for (int nn = 0; nn < 501; nn++) {
    double m = nn - 250.0;
    double xx = fc * m;
    double snc = (nn == 250) ? 1.0 : std::sin(M_PI * xx) / (M_PI * xx);
    double r = (2.0 * nn) / 500.0 - 1.0;
    double w = bessel_i0(5.0 * std::sqrt(std::max(0.0, 1.0 - r * r))) / denom;
    h[nn] = fc * snc * w; sum += h[nn];
  }
  for (int nn = 0; nn < 25; nn++) fa.h[nn] = 0.0f;          // n_pre_pad = 25
  for (int nn = 0; nn < 501; nn++) fa.h[25 + nn] = (float)(h[nn] / sum * 16.0);
}

// ---------------- device helpers ----------------
__device__ inline double waveReduceSum(double v) {
  #pragma unroll
  for (int off = 32; off > 0; off >>= 1) v += __shfl_down(v, off, 64);
  return v;
}

__device__ inline void cpow_int(double br, double bi, int n, double& rr_, double& ri_) {
  double rr = 1.0, ri = 0.0;
  while (n) {
    if (n & 1) { double t = rr * br - ri * bi; ri = rr * bi + ri * br; rr = t; }
    double t2 = br * br - bi * bi; bi = 2.0 * br * bi; br = t2;
    n >>= 1;
  }
  rr_ = rr; ri_ = ri;
}

// ---------------- kernel 1: chansel + demean, PE table, out-zero (merged) -----
__global__ __launch_bounds__(256) void k_chansel_pe(const float* __restrict__ x,
                                                    float* __restrict__ xs,
                                                    float* __restrict__ pe,
                                                    float* __restrict__ out) {
  int gid = blockIdx.x;
  if (gid < 500) {
    int idx = gid * 256 + threadIdx.x;
    int b = idx / 2000, t = idx % 2000;
    const int ch[10] = {126, 125, 48, 112, 67, 93, 10, 61, 39, 108};
    const float* xb = x + (size_t)b * 128 * 2000;
    float v[10]; float s = 0.f;
    #pragma unroll
    for (int c = 0; c < 10; c++) { v[c] = xb[ch[c] * 2000 + t]; s += v[c]; }
    s *= 0.1f;
    #pragma unroll
    for (int c = 0; c < 10; c++) xs[((size_t)b * 10 + c) * 2000 + t] = v[c] - s;
  } else {
    int i = (gid - 500) * 256 + threadIdx.x;    // [0, 20480)
    int t = i >> 4, d = i & 15, j = d >> 1;
    double div = exp(-((double)(2 * j)) * 0.5756462732485114); // ln(10000)/16
    double a = (double)t * div;
    pe[i] = (float)((d & 1) ? cos(a) : sin(a));
    if (gid == 579 && threadIdx.x < 64) out[threadIdx.x] = 0.f;
  }
}

// ---------------- kernel 2: filtfilt, 128 chunks x 16 steps, eigen prefix -----
#define XR(t) xr[(t) + ((t) >> 5)]
#define YF(t) yf[(t) + ((t) >> 5)]
__global__ __launch_bounds__(128) void k_filtfilt(float* __restrict__ xs,
                                                  FiltArg c, CorArg co, EigArg eg) {
  __shared__ float xr[2112];      // extended input seq (padded)
  __shared__ double yf[2112];     // corrected forward output (padded)
  __shared__ double wsum[3][2];   // wave0 inclusive totals per section
  int r = blockIdx.x;
  int gk = threadIdx.x;           // global chunk id 0..127
  int lane = gk & 63;
  int wv = gk >> 6;
  float* x = xs + (size_t)r * 2000;

  float x0f = x[0], xlf = x[1999];
  for (int t = gk; t < 2048; t += 128) {
    float v;
    if (t < 21)        v = 2.f * x0f - x[21 - t];
    else if (t < 2021) v = x[t - 21];
    else if (t < 2042) v = 2.f * xlf - x[4019 - t];
    else               v = 0.f;
    XR(t) = v;
  }
  __syncthreads();

  double b0[3], b1[3], b2[3], a1[3], a2[3];
  #pragma unroll
  for (int s = 0; s < 3; s++) {
    b0[s] = c.b0[s]; b1[s] = c.b1[s]; b2[s] = c.b2[s];
    a1[s] = c.a1[s]; a2[s] = c.a2[s];
  }
  auto step = [&](double* z, double v) -> double {
    #pragma unroll
    for (int s = 0; s < 3; s++) {
      double y = b0[s] * v + z[2 * s];
      z[2 * s]     = b1[s] * v - a1[s] * y + z[2 * s + 1];
      z[2 * s + 1] = b2[s] * v - a2[s] * y;
      v = y;
    }
    return v;
  };

  auto eigscan = [&](double seed, const double* F, double* zst) {
    double G[6];
    #pragma unroll
    for (int i = 0; i < 6; i++) {
      double s = 0.0;
      #pragma unroll
      for (int j = 0; j < 6; j++) s += eg.Pinv[i * 6 + j] * F[j];
      G[i] = s;
    }
    double tre[3], tim[3], sre[3], sim[3];
    #pragma unroll
    for (int s3 = 0; s3 < 3; s3++) {
      double gre = G[2 * s3], gim = -G[2 * s3 + 1];
      double mre, mim;                                  // λ^{-gk}
      cpow_int(eg.lami_re[s3], eg.lami_im[s3], gk, mre, mim);
      tre[s3] = mre * gre - mim * gim;
      tim[s3] = mre * gim + mim * gre;
      double pr = tre[s3], pi = tim[s3];
      #pragma unroll
      for (int off = 1; off < 64; off <<= 1) {
        double ore = __shfl_up(pr, off, 64);
        double oim = __shfl_up(pi, off, 64);
        pr += (lane >= off) ? ore : 0.0;
        pi += (lane >= off) ? oim : 0.0;
      }
      sre[s3] = pr; sim[s3] = pi;
      if (wv == 0 && lane == 63) { wsum[s3][0] = pr; wsum[s3][1] = pi; }
    }
    __syncthreads();
    double coord[6];
    #pragma unroll
    for (int s3 = 0; s3 < 3; s3++) {
      double inc_re = sre[s3] + (wv ? wsum[s3][0] : 0.0);
      double inc_im = sim[s3] + (wv ? wsum[s3][1] : 0.0);
      double Sre = inc_re - tre[s3], Sim = inc_im - tim[s3];
      double c0re = seed * eg.czi[2 * s3];
      double c0im = -seed * eg.czi[2 * s3 + 1];
      double lkre, lkim;
      cpow_int(eg.lam_re[s3], eg.lam_im[s3], gk, lkre, lkim);
      double lm1re = lkre * eg.lami_re[s3] - lkim * eg.lami_im[s3];
      double lm1im = lkre * eg.lami_im[s3] + lkim * eg.lami_re[s3];
      if (gk == 0) { lm1re = 0.0; lm1im = 0.0; }
      double cre = lkre * c0re - lkim * c0im + lm1re * Sre - lm1im * Sim;
      double cim = lkre * c0im + lkim * c0re + lm1re * Sim + lm1im * Sre;
      coord[2 * s3] = cre;
      coord[2 * s3 + 1] = -cim;
    }
    #pragma unroll
    for (int i = 0; i < 6; i++) {
      double s = 0.0;
      #pragma unroll
      for (int j = 0; j < 6; j++) s += eg.Pm[i * 6 + j] * coord[j];
      zst[i] = s;
    }
  };

  int t0 = gk * 16;
  double z[6], yreg[16], zst[6];

  #pragma unroll
  for (int i = 0; i < 6; i++) z[i] = 0.0;
  for (int i = 0; i < 16; i++) yreg[i] = step(z, (double)XR(t0 + i));
  eigscan((double)XR(0), z, zst);
  for (int i = 0; i < 16; i++) {
    double corr = 0.0;
    #pragma unroll
    for (int j = 0; j < 6; j++) corr += co.CA[i * 6 + j] * zst[j];
    YF(t0 + i) = yreg[i] + corr;
  }
  __syncthreads();

  auto rin = [&](int j) -> double { return (j <= 2041) ? YF(2041 - j) : 0.0; };
  double seedB = YF(2041);
  #pragma unroll
  for (int i = 0; i < 6; i++) z[i] = 0.0;
  for (int i = 0; i < 16; i++) yreg[i] = step(z, rin(t0 + i));
  eigscan(seedB, z, zst);
  for (int i = 0; i < 16; i++) {
    int j = t0 + i;
    if (j >= 21 && j <= 2020) {
      double corr = 0.0;
      #pragma unroll
      for (int jj = 0; jj < 6; jj++) corr += co.CA[i * 6 + jj] * zst[jj];
      x[2020 - j] = (float)(yreg[i] + corr);   // reversed + trimmed
    }
  }
}

// ---------------- kernel 3: polyphase resample + tanh + per-row normalize ----
__global__ __launch_bounds__(256) void k_resample_norm(const float* __restrict__ xf,
                                                       float* __restrict__ xn,
                                                       FirArg fa) {
  __shared__ float xl[2000];
  __shared__ float hl[526];
  int r = blockIdx.x;                         // 640 rows
  const float* x = xf + (size_t)r * 2000;
  for (int i = threadIdx.x; i < 2000; i += 256) xl[i] = x[i];
  for (int i = threadIdx.x; i < 526; i += 256) hl[i] = fa.h[i];
  __syncthreads();
  float vals[5];
  #pragma unroll
  for (int kk = 0; kk < 5; kk++) {
    int o = threadIdx.x + kk * 256;           // 1280 outputs per row
    int P = 25 * (o + 11);
    int phase = P & 15;
    float acc = 0.f;
    for (int m = phase; m <= 525; m += 16) {
      int idx = (P - m) >> 4;
      if (idx >= 0 && idx < 2000) acc += hl[m] * xl[idx];
    }
    vals[kk] = tanhf(acc);
  }
  double s = 0.0, ss = 0.0;
  #pragma unroll
  for (int kk = 0; kk < 5; kk++) {
    s += (double)vals[kk]; ss += (double)vals[kk] * (double)vals[kk];
  }
  s = waveReduceSum(s); ss = waveReduceSum(ss);
  __shared__ double red[8];
  int wid = threadIdx.x >> 6, lane = threadIdx.x & 63;
  if (lane == 0) { red[wid] = s; red[4 + wid] = ss; }
  __syncthreads();
  double S = red[0] + red[1] + red[2] + red[3];
  double SS = red[4] + red[5] + red[6] + red[7];
  double mean = S / 1280.0;
  double var = (SS - 1280.0 * mean * mean) / 1279.0;
  double sd = fmax(sqrt(fmax(var, 0.0)), 1e-6);
  float fmean = (float)mean, finv = (float)(1.0 / sd);
  #pragma unroll
  for (int kk = 0; kk < 5; kk++)
    xn[(size_t)r * 1280 + threadIdx.x + kk * 256] = (vals[kk] - fmean) * finv;
}

// ---------------- kernel 4: conv1d + relu + LN + PE + QKV (K,V emitted f16) ---
__global__ __launch_bounds__(256) void k_conv_ln_pe_qkv(const float* __restrict__ xn,
    const float* __restrict__ cw, const float* __restrict__ cb,
    const float* __restrict__ g0, const float* __restrict__ bt0,
    const float* __restrict__ wqkv, const float* __restrict__ bqkv,
    const float* __restrict__ pe,
    float* __restrict__ x0, float* __restrict__ Q,
    _Float16* __restrict__ Kp, _Float16* __restrict__ Vt_g) {
  __shared__ float w[480], bias[16], gg[16], gb[16];
  __shared__ float wq[768], bq[48];
  for (int i = threadIdx.x; i < 480; i += 256) w[i] = cw[i];
  for (int i = threadIdx.x; i < 768; i += 256) wq[i] = wqkv[i];
  if (threadIdx.x < 16) {
    bias[threadIdx.x] = cb[threadIdx.x];
    gg[threadIdx.x] = g0[threadIdx.x];
    gb[threadIdx.x] = bt0[threadIdx.x];
  }
  if (threadIdx.x < 48) bq[threadIdx.x] = bqkv[threadIdx.x];
  __syncthreads();
  int idx = blockIdx.x * 256 + threadIdx.x;
  int b = idx / 1280, t = idx % 1280;
  const float* xb = xn + (size_t)b * 10 * 1280;
  float in[10][3];
  #pragma unroll
  for (int i = 0; i < 10; i++)
    #pragma unroll
    for (int k = 0; k < 3; k++) {
      int tt = t - 1 + k;
      in[i][k] = (tt >= 0 && tt < 1280) ? xb[i * 1280 + tt] : 0.f;
    }
  float o[16];
  #pragma unroll
  for (int oc = 0; oc < 16; oc++) {
    float a = bias[oc];
    #pragma unroll
    for (int i = 0; i < 10; i++)
      #pragma unroll
      for (int k = 0; k < 3; k++) a += in[i][k] * w[oc * 30 + i * 3 + k];
    o[oc] = fmaxf(a, 0.f);
  }
  float mu = 0.f;
  #pragma unroll
  for (int d = 0; d < 16; d++) mu += o[d];
  mu *= (1.f / 16.f);
  float var = 0.f;
  #pragma unroll
  for (int d = 0; d < 16; d++) { float dd = o[d] - mu; var += dd * dd; }
  var *= (1.f / 16.f);
  float inv = 1.f / sqrtf(var + 1e-5f);
  float xv[16];
  float* outp = x0 + (size_t)idx * 16;
  const float* pep = pe + t * 16;
  #pragma unroll
  for (int d = 0; d < 16; d++) {
    xv[d] = (o[d] - mu) * inv * gg[d] + gb[d] + pep[d];
    outp[d] = xv[d];
  }
  float* qp = Q + (size_t)idx * 16;
  #pragma unroll
  for (int j = 0; j < 16; j++) {
    float a = bq[j];
    #pragma unroll
    for (int d = 0; d < 16; d++) a += xv[d] * wq[j * 16 + d];
    qp[j] = a;
  }
  {
    _Float16* kp = Kp + (size_t)idx * 32;
    #pragma unroll
    for (int j = 0; j < 16; j++) {
      float a = bq[16 + j];
      #pragma unroll
      for (int d = 0; d < 16; d++) a += xv[d] * wq[(16 + j) * 16 + d];
      kp[j] = (_Float16)a;
    }
    f16x8 zz;
    #pragma unroll
    for (int j = 0; j < 8; j++) zz[j] = (_Float16)0.f;
    *(f16x8*)&kp[16] = zz;
    *(f16x8*)&kp[24] = zz;
  }
  {
    _Float16* vt = Vt_g + (size_t)b * 16 * 1280 + t;
    #pragma unroll
    for (int j = 0; j < 16; j++) {
      float a = bq[32 + j];
      #pragma unroll
      for (int d = 0; d < 16; d++) a += xv[d] * wq[(32 + j) * 16 + d];
      vt[j * 1280] = (_Float16)a;
    }
  }
}

// ---------------- kernel 5: MFMA attention + combine + pool (fused) -----------
// Ks2 stride padded 32 -> 40 halves: the stride-32 read pattern
// (keyoff+col)*32+quad*8 gave dword addr col*16+quad*4 -> col*16 mod 32 in
// {0,16} -> 8-way bank conflicts (the 4.96M cycles). Stride 40: col*20 mod 32
// has period 8 -> 2 lanes/window = 2-way = free. 80B stride keeps 16B align.
#define ATT_SHIFT 12.0f
__global__ __launch_bounds__(256) void k_attn_combine(const float* __restrict__ Q,
    const _Float16* __restrict__ Kp, const _Float16* __restrict__ Vt_g,
    const float* __restrict__ x0,
    const float* __restrict__ wo, const float* __restrict__ bo,
    const float* __restrict__ w1, const float* __restrict__ b1,
    const float* __restrict__ w2, const float* __restrict__ b2,
    const float* __restrict__ g1, const float* __restrict__ bb1,
    const float* __restrict__ g2, const float* __restrict__ bb2,
    const float* __restrict__ wfc, const float* __restrict__ bfc,
    float* __restrict__ out) {
  __shared__ __align__(16) _Float16 Ks2[64 * 40];    // [key][d0..31] stride 40
  __shared__ __align__(16) _Float16 Vt[16 * 72];     // [d][key]
  __shared__ __align__(16) _Float16 Pld[4][16 * 40]; // per-wave [qrow][key32]
  __shared__ float Aly[64][17];                      // attn out rows (padded)
  __shared__ float swo[256], sw1[512], sw2[512];
  __shared__ float sbo[16], sb1[32], sb2[16], sg1[16], sbb1[16], sg2[16], sbb2[16];
  __shared__ float swf[16];
  int tid = threadIdx.x;
  int b  = blockIdx.x / 20;
  int rg = blockIdx.x % 20;
  int wv = tid >> 6;
  int lane = tid & 63;
  int col = lane & 15;
  int quad = lane >> 4;
  size_t base = (size_t)b * 1280;
  int row0 = rg * 64 + wv * 16;

  // stage combine weights (overlaps first tile staging)
  swo[tid] = wo[tid];
  for (int i = tid; i < 512; i += 256) { sw1[i] = w1[i]; sw2[i] = w2[i]; }
  if (tid < 16) {
    sbo[tid] = bo[tid]; sb2[tid] = b2[tid];
    sg1[tid] = g1[tid]; sbb1[tid] = bb1[tid];
    sg2[tid] = g2[tid]; sbb2[tid] = bb2[tid];
    swf[tid] = wfc[tid];
  }
  if (tid < 32) sb1[tid] = b1[tid];

  f16x8 qf;
  #pragma unroll
  for (int j = 0; j < 8; j++) qf[j] = (_Float16)0.f;
  if (quad < 2) {
    const float* qp = Q + (base + row0 + col) * 16 + quad * 8;
    #pragma unroll
    for (int j = 0; j < 8; j++) qf[j] = (_Float16)(0.25f * qp[j]);
  }
  f32x4 oacc = {0.f, 0.f, 0.f, 0.f};
  float lacc = 0.f;

  const _Float16* vt_b = Vt_g + (size_t)b * 16 * 1280;

  for (int s = 0; s < 20; s++) {
    __syncthreads();
    // Ks2 staging: thread tid -> key=tid>>2, part=tid&3; write addr
    // key*40+part*8 halves (16B aligned; dword addr key*20+part*4 -> 2-way)
    {
      int key = tid >> 2, part = tid & 3;
      *(f16x8*)&Ks2[key * 40 + part * 8] =
          *(const f16x8*)(Kp + (base + s * 64) * 32 + tid * 8);
    }
    if (tid < 128) {
      int d = tid >> 3, qc = tid & 7;
      *(f16x8*)&Vt[d * 72 + qc * 8] =
          *(const f16x8*)(vt_b + d * 1280 + s * 64 + qc * 8);
    }
    __syncthreads();
    #pragma unroll
    for (int c = 0; c < 2; c++) {
      #pragma unroll
      for (int t = 0; t < 2; t++) {
        int keyoff = c * 32 + t * 16;
        f16x8 af = *(f16x8*)&Ks2[(keyoff + col) * 40 + quad * 8];
        f32x4 sf = {0.f, 0.f, 0.f, 0.f};
        sf = __builtin_amdgcn_mfma_f32_16x16x32_f16(af, qf, sf, 0, 0, 0);
        f16x4 ph;
        float psum = 0.f;
        #pragma unroll
        for (int r = 0; r < 4; r++) {
          float p = __expf(sf[r] - ATT_SHIFT);
          psum += p;
          ph[r] = (_Float16)p;
        }
        lacc += psum;
        *(f16x4*)&Pld[wv][col * 40 + t * 16 + quad * 4] = ph;
      }
      __syncthreads();
      f16x8 pf = *(f16x8*)&Pld[wv][col * 40 + quad * 8];
      f16x8 vf = *(f16x8*)&Vt[col * 72 + c * 32 + quad * 8];
      oacc = __builtin_amdgcn_mfma_f32_16x16x32_f16(pf, vf, oacc, 0, 0, 0);
      __syncthreads();
    }
  }
  lacc += __shfl_xor(lacc, 16, 64);
  lacc += __shfl_xor(lacc, 32, 64);
  #pragma unroll
  for (int r = 0; r < 4; r++) {
    float lr = __shfl(lacc, quad * 4 + r, 64);
    Aly[wv * 16 + quad * 4 + r][col] = oacc[r] / lr;
  }
  __syncthreads();

  // ---- epilogue: wave 0, one thread per row ----
  if (tid < 64) {
    int grow = rg * 64 + tid;                 // row within batch
    size_t goff = (base + grow) * 16;
    float a[16];
    #pragma unroll
    for (int d = 0; d < 16; d++) a[d] = Aly[tid][d];
    float h[16];
    const float* xr = x0 + goff;
    #pragma unroll
    for (int d = 0; d < 16; d++) {
      float o = sbo[d];
      #pragma unroll
      for (int e = 0; e < 16; e++) o += a[e] * swo[d * 16 + e];
      h[d] = xr[d] + o;
    }
    float mu = 0.f;
    #pragma unroll
    for (int d = 0; d < 16; d++) mu += h[d];
    mu *= (1.f / 16.f);
    float var = 0.f;
    #pragma unroll
    for (int d = 0; d < 16; d++) { float dd = h[d] - mu; var += dd * dd; }
    var *= (1.f / 16.f);
    float inv = 1.f / sqrtf(var + 1e-5f);
    float x1[16];
    #pragma unroll
    for (int d = 0; d < 16; d++) x1[d] = (h[d] - mu) * inv * sg1[d] + sbb1[d];
    float t1[32];
    #pragma unroll
    for (int j = 0; j < 32; j++) {
      float u = sb1[j];
      #pragma unroll
      for (int d = 0; d < 16; d++) u += x1[d] * sw1[j * 16 + d];
      t1[j] = fmaxf(u, 0.f);
    }
    float h2[16];
    #pragma unroll
    for (int d = 0; d < 16; d++) {
      float u = sb2[d];
      #pragma unroll
      for (int j = 0; j < 32; j++) u += t1[j] * sw2[d * 32 + j];
      h2[d] = x1[d] + u;
    }
    mu = 0.f;
    #pragma unroll
    for (int d = 0; d < 16; d++) mu += h2[d];
    mu *= (1.f / 16.f);
    var = 0.f;
    #pragma unroll
    for (int d = 0; d < 16; d++) { float dd = h2[d] - mu; var += dd * dd; }
    var *= (1.f / 16.f);
    inv = 1.f / sqrtf(var + 1e-5f);
    float pv = 0.f;
    #pragma unroll
    for (int d = 0; d < 16; d++)
      pv += ((h2[d] - mu) * inv * sg2[d] + sbb2[d]) * swf[d];
    double part = waveReduceSum((double)pv);
    if (tid == 0) {
      float add = (float)(part / 1280.0);
      if (blockIdx.x % 20 == 0) add += bfc[0];
      atomicAdd(&out[b], add);
    }
  }
}

// ---------------- launch ------------------------------------------------------
extern "C" void kernel_launch(void* const* d_in, const int* in_sizes, int n_in,
                              void* d_out, int out_size, void* d_ws, size_t ws_size,
                              hipStream_t stream) {
  const float* x    = (const float*)d_in[0];
  const float* cw   = (const float*)d_in[1];
  const float* cb   = (const float*)d_in[2];
  const float* g0   = (const float*)d_in[3];
  const float* bt0  = (const float*)d_in[4];
  const float* wqkv = (const float*)d_in[5];
  const float* bqkv = (const float*)d_in[6];
  const float* wo   = (const float*)d_in[7];
  const float* bo   = (const float*)d_in[8];
  const float* w1   = (const float*)d_in[9];
  const float* b1   = (const float*)d_in[10];
  const float* w2   = (const float*)d_in[11];
  const float* b2   = (const float*)d_in[12];
  const float* g1   = (const float*)d_in[13];
  const float* bb1  = (const float*)d_in[14];
  const float* g2   = (const float*)d_in[15];
  const float* bb2  = (const float*)d_in[16];
  const float* wfc  = (const float*)d_in[17];
  const float* bfc  = (const float*)d_in[18];
  float* out = (float*)d_out;

  float* ws = (float*)d_ws;
  float* xs = ws;                       // 640*2000 = 1,280,000 (filtered in-place)
  float* y1 = xs + 1280000;             // spacer (dead)
  float* xn = y1 + 1306880;             // 640*1280   =   819,200
  float* x0 = xn + 819200;              // 64*1280*16 = 1,310,720
  float* Q  = x0 + 1310720;
  _Float16* Kp   = (_Float16*)(Q + 1310720);      // 64*1280*32 f16 = 1,310,720 floats
  _Float16* Vt_g = (_Float16*)(Q + 2621440);      // 64*16*1280 f16 =   655,360 floats
  float* pe = Q + 2621440 + 655360;     // 1280*16 = 20,480  (total ~34 MB)

  FiltArg fc; CorArg co; EigArg eg; FirArg fa;
  build_filt(fc, co);
  build_eig(fc, eg);
  design_fir(fa);

  k_chansel_pe<<<580, 256, 0, stream>>>(x, xs, pe, out);
  k_filtfilt<<<640, 128, 0, stream>>>(xs, fc, co, eg);
  k_resample_norm<<<640, 256, 0, stream>>>(xs, xn, fa);
  k_conv_ln_pe_qkv<<<320, 256, 0, stream>>>(xn, cw, cb, g0, bt0, wqkv, bqkv,
                                            pe, x0, Q, Kp, Vt_g);
  k_attn_combine<<<1280, 256, 0, stream>>>(Q, Kp, Vt_g, x0, wo, bo, w1, b1,
                                           w2, b2, g1, bb1, g2, bb2, wfc, bfc,
                                           out);
}